// Round 2
// baseline (2094.719 us; speedup 1.0000x reference)
//
#include <hip/hip_runtime.h>
#include <stdint.h>
#include <math.h>

// EncoderTransformerBlock (Swin-like, 8x8 windows, C=256, heads=8) on gfx950.
// v2: workspace-slim pipeline (peak 270,008,320 bytes = 258 MB):
//  k_wconv                 : fp32 weights -> bf16            @ OFF_WB
//  k_ln1_fft               : LN1 + window partition + rfft -> T (136MB) @ 0
//  per chunk c (8 chunks of 256 windows):
//    gemm128<0>            : QKVc = T_chunk @ qkv_w^T + b    (33280x768 bf16, 51MB)
//    attn_spatial          : window attention + rel-pos bias -> Yw rows
//    attn_spec             : spectral attn (66 tok) + in-LDS irfft, Yw += ...
//  gemm128<1>              : X2 = Yw @ proj_w^T + b + x (raster scatter, fp32 @0 over dead T)
//  k_ln2                   : T2 = LN2(X2) bf16
//  per pass p (4 passes of 256 hidden cols):
//    gemm128<2>            : HIDq = gelu(T2 @ fc1_w[p]^T + b)
//    gemm128<3|4>          : out (=|+=) HIDq @ fc2_w[:,p]^T (+ b + X2 on p=0)

using short8  = __attribute__((ext_vector_type(8))) short;
using short4v = __attribute__((ext_vector_type(4))) short;
using f32x4   = __attribute__((ext_vector_type(4))) float;

#define DEV __device__ __forceinline__

static constexpr float ATT_SCALE = 0.17677669529663688f;   // 32^-0.5
static constexpr float TWO_PI_64 = 0.09817477042468103f;   // 2*pi/64

DEV short f2bf(float f) {
  union { float f; uint32_t u; } x; x.f = f;
  uint32_t u = x.u;
  uint32_t r = u + 0x7fffu + ((u >> 16) & 1u);
  if ((u & 0x7f800000u) == 0x7f800000u) r = u;
  return (short)(r >> 16);
}
DEV float bf2f(short s) {
  union { uint32_t u; float f; } x;
  x.u = ((uint32_t)(uint16_t)s) << 16;
  return x.f;
}

// ---------------- weight fp32->bf16 ----------------
__global__ __launch_bounds__(256)
void k_wconv(const float* __restrict__ qw, const float* __restrict__ pw,
             const float* __restrict__ f1, const float* __restrict__ f2,
             short* __restrict__ o) {
  const int i = blockIdx.x * 256 + threadIdx.x;
  float v;
  if (i < 196608) v = qw[i];
  else if (i < 262144) v = pw[i - 196608];
  else if (i < 524288) v = f1[i - 262144];
  else v = f2[i - 524288];
  o[i] = f2bf(v);
}

// ---------------- LN1 + window partition + rfft ----------------
__global__ __launch_bounds__(256)
void k_ln1_fft(const float* __restrict__ x, const float* __restrict__ nw,
               const float* __restrict__ nb, short* __restrict__ T) {
  __shared__ short xn[64 * 256];
  __shared__ float ct[64], st[64], wS[256], bS[256];
  const int tid = threadIdx.x;
  const int wdw = blockIdx.x;
  const int bb = wdw >> 10, rem = wdw & 1023, wy = rem >> 5, wx = rem & 31;
  if (tid < 64) {
    float ang = (float)tid * TWO_PI_64;
    ct[tid] = cosf(ang);
    st[tid] = sinf(ang);
  }
  wS[tid] = nw[tid];
  bS[tid] = nb[tid];
  __syncthreads();
  const int g = tid >> 4, l16 = tid & 15;
  #pragma unroll
  for (int it = 0; it < 4; ++it) {
    const int t = it * 16 + g;
    const int gy = (wy << 3) + (t >> 3), gx = (wx << 3) + (t & 7);
    const size_t rrow = ((size_t)bb * 256 + gy) * 256 + gx;
    const float4* xv4 = (const float4*)(x + rrow * 256);
    float4 v[4];
    float s = 0.f, ss = 0.f;
    #pragma unroll
    for (int j = 0; j < 4; ++j) {
      v[j] = xv4[l16 * 4 + j];
      s  += v[j].x + v[j].y + v[j].z + v[j].w;
      ss += v[j].x * v[j].x + v[j].y * v[j].y + v[j].z * v[j].z + v[j].w * v[j].w;
    }
    #pragma unroll
    for (int m = 1; m < 16; m <<= 1) {
      s  += __shfl_xor(s, m);
      ss += __shfl_xor(ss, m);
    }
    const float mean = s * 0.00390625f;
    const float var  = ss * 0.00390625f - mean * mean;
    const float rs   = rsqrtf(var + 1e-5f);
    short tmp[16];
    #pragma unroll
    for (int j = 0; j < 4; ++j) {
      const float* vp = (const float*)&v[j];
      #pragma unroll
      for (int e = 0; e < 4; ++e) {
        const int c0 = l16 * 16 + j * 4 + e;
        tmp[j * 4 + e] = f2bf((vp[e] - mean) * rs * wS[c0] + bS[c0]);
      }
    }
    short8* dl = (short8*)(xn + t * 256 + l16 * 16);
    short8* dg = (short8*)(T + ((size_t)wdw * 130 + t) * 256 + l16 * 16);
    dl[0] = ((short8*)tmp)[0]; dl[1] = ((short8*)tmp)[1];
    dg[0] = ((short8*)tmp)[0]; dg[1] = ((short8*)tmp)[1];
  }
  __syncthreads();
  // rfft over tokens (ortho): rows 64..96 real, 97..129 imag (negated sin)
  const int c = tid;
  float xs[64];
  #pragma unroll
  for (int n = 0; n < 64; ++n) xs[n] = bf2f(xn[n * 256 + c]);
  const size_t baseR = ((size_t)wdw * 130 + 64) * 256 + c;
  for (int k = 0; k <= 32; ++k) {
    float re = 0.f, im = 0.f;
    int m = 0;
    #pragma unroll
    for (int n = 0; n < 64; ++n) {
      re = fmaf(ct[m], xs[n], re);
      im = fmaf(st[m], xs[n], im);
      m = (m + k) & 63;
    }
    T[baseR + (size_t)k * 256]        = f2bf(re * 0.125f);
    T[baseR + (size_t)(k + 33) * 256] = f2bf(-im * 0.125f);
  }
}

// ---------------- 128x128 MFMA GEMM (reg-staged LDS) ----------------
// A: MxK bf16 (row stride lda), Bt: NxK bf16 (row stride ldb)
// EPI: 0 +bias->bf16 | 1 +bias+x(raster scatter)->f32 | 2 +bias,gelu->bf16
//      3 +bias+addf->f32 | 4 accumulate (out += val, no bias)
template<int EPI>
__global__ __launch_bounds__(256)
void gemm128(const short* __restrict__ A, const short* __restrict__ Bt,
             const float* __restrict__ bias, const float* __restrict__ addf,
             short* __restrict__ outb, float* __restrict__ outf,
             const int N, const int K, const int lda, const int ldb) {
  __shared__ short As[128 * 32];
  __shared__ short Bs[128 * 32];
  const int tid = threadIdx.x;
  const int w = tid >> 6, l = tid & 63;
  const int lr = l & 15, lg = l >> 4;
  const int bm = blockIdx.y << 7, bn = blockIdx.x << 7;
  const int wm = (w >> 1) << 6, wn = (w & 1) << 6;
  f32x4 acc[4][4] = {};
  const int rloc = l >> 2, kc = (l & 3) << 3;
  for (int kt = 0; kt < K; kt += 32) {
    #pragma unroll
    for (int i = 0; i < 2; ++i) {
      const int seg = i * 4 + w;
      const int row = (seg << 4) + rloc;
      const short8 ra = *(const short8*)(A  + (size_t)(bm + row) * lda + kt + kc);
      const short8 rb = *(const short8*)(Bt + (size_t)(bn + row) * ldb + kt + kc);
      *(short8*)(As + seg * 512 + l * 8) = ra;
      *(short8*)(Bs + seg * 512 + l * 8) = rb;
    }
    __syncthreads();
    short8 af[4], bfr[4];
    #pragma unroll
    for (int mi = 0; mi < 4; ++mi)
      af[mi] = *(const short8*)(As + ((wm + (mi << 4) + lr) << 5) + (lg << 3));
    #pragma unroll
    for (int ni = 0; ni < 4; ++ni)
      bfr[ni] = *(const short8*)(Bs + ((wn + (ni << 4) + lr) << 5) + (lg << 3));
    #pragma unroll
    for (int mi = 0; mi < 4; ++mi)
      #pragma unroll
      for (int ni = 0; ni < 4; ++ni)
        acc[mi][ni] = __builtin_amdgcn_mfma_f32_16x16x32_bf16(af[mi], bfr[ni], acc[mi][ni], 0, 0, 0);
    __syncthreads();
  }
  #pragma unroll
  for (int mi = 0; mi < 4; ++mi) {
    #pragma unroll
    for (int ni = 0; ni < 4; ++ni) {
      const f32x4 v = acc[mi][ni];
      const int col = bn + wn + (ni << 4) + lr;
      const int row0 = bm + wm + (mi << 4) + (lg << 2);
      const float bc = (EPI == 4) ? 0.f : bias[col];
      #pragma unroll
      for (int r = 0; r < 4; ++r) {
        const int row = row0 + r;
        float val = v[r] + bc;
        if (EPI == 0) {
          outb[(size_t)row * N + col] = f2bf(val);
        } else if (EPI == 2) {
          float gl = 0.5f * val * (1.0f + erff(val * 0.7071067811865475f));
          outb[(size_t)row * N + col] = f2bf(gl);
        } else if (EPI == 1) {
          const int ww = row >> 6, t = row & 63;
          const int b2 = ww >> 10, rem = ww & 1023;
          const int gy = ((rem >> 5) << 3) + (t >> 3);
          const int gx = ((rem & 31) << 3) + (t & 7);
          const size_t rr = ((size_t)b2 * 256 + gy) * 256 + gx;
          outf[rr * 256 + col] = val + addf[rr * 256 + col];
        } else if (EPI == 3) {
          outf[(size_t)row * N + col] = val + addf[(size_t)row * N + col];
        } else {
          outf[(size_t)row * N + col] += val;
        }
      }
    }
  }
}

// ---------------- spatial window attention (4 waves = 4 heads) ----------------
// S^T = mfma(K,Q): softmax k-reduction is lane-local + 2 shfl. Out^T = mfma(V^T,P^T).
__global__ __launch_bounds__(256)
void attn_spatial(const short* __restrict__ QKV, const float* __restrict__ rpb,
                  short* __restrict__ Yw, const size_t yrow_base) {
  constexpr int LDP = 72;
  __shared__ short vt_s[4 * 32 * LDP];
  __shared__ short pl_s[4 * 64 * LDP];
  const int tid = threadIdx.x;
  const int w = tid >> 6, l = tid & 63;
  const int lr = l & 15, lg = l >> 4;
  const int w_l = blockIdx.x;
  const int h = blockIdx.y * 4 + w;
  const size_t rowbase = (size_t)w_l * 130;
  short* vt = vt_s + w * 32 * LDP;
  short* pl = pl_s + w * 64 * LDP;
  short* ostage = pl_s;

  #pragma unroll
  for (int i = 0; i < 4; ++i) {
    const int chunk = i * 64 + l;
    const int tok = chunk >> 2, d0 = (chunk & 3) << 3;
    const short8 vv = *(const short8*)(QKV + (rowbase + tok) * 768 + 512 + h * 32 + d0);
    #pragma unroll
    for (int j = 0; j < 8; ++j) vt[(d0 + j) * LDP + tok] = vv[j];
  }
  short8 bq[4], akf[4];
  #pragma unroll
  for (int ni = 0; ni < 4; ++ni)
    bq[ni] = *(const short8*)(QKV + (rowbase + (ni << 4) + lr) * 768 + h * 32 + (lg << 3));
  #pragma unroll
  for (int mi = 0; mi < 4; ++mi)
    akf[mi] = *(const short8*)(QKV + (rowbase + (mi << 4) + lr) * 768 + 256 + h * 32 + (lg << 3));

  #pragma unroll
  for (int ni = 0; ni < 4; ++ni) {
    f32x4 s[4];
    #pragma unroll
    for (int mi = 0; mi < 4; ++mi) {
      f32x4 z = {};
      s[mi] = __builtin_amdgcn_mfma_f32_16x16x32_bf16(akf[mi], bq[ni], z, 0, 0, 0);
    }
    const int q = (ni << 4) + lr;
    float lv[4][4];
    float mx = -3.0e30f;
    #pragma unroll
    for (int mi = 0; mi < 4; ++mi) {
      #pragma unroll
      for (int r = 0; r < 4; ++r) {
        const int mm = (mi << 4) + (lg << 2) + r;
        const int dy = (q >> 3) - (mm >> 3) + 7;
        const int dx = (q & 7) - (mm & 7) + 7;
        float tt = s[mi][r] * ATT_SCALE + rpb[(dy * 15 + dx) * 8 + h];
        lv[mi][r] = tt;
        mx = fmaxf(mx, tt);
      }
    }
    mx = fmaxf(mx, __shfl_xor(mx, 16));
    mx = fmaxf(mx, __shfl_xor(mx, 32));
    float sum = 0.f;
    #pragma unroll
    for (int mi = 0; mi < 4; ++mi)
      #pragma unroll
      for (int r = 0; r < 4; ++r) {
        const float p = __expf(lv[mi][r] - mx);
        lv[mi][r] = p;
        sum += p;
      }
    sum += __shfl_xor(sum, 16);
    sum += __shfl_xor(sum, 32);
    const float inv = 1.0f / sum;
    #pragma unroll
    for (int mi = 0; mi < 4; ++mi) {
      short4v pk;
      #pragma unroll
      for (int r = 0; r < 4; ++r) pk[r] = f2bf(lv[mi][r] * inv);
      *(short4v*)(pl + q * LDP + (mi << 4) + (lg << 2)) = pk;
    }
  }
  __syncthreads();

  f32x4 o[2][4] = {};
  #pragma unroll
  for (int ks = 0; ks < 2; ++ks) {
    short8 av[2], pb[4];
    #pragma unroll
    for (int di = 0; di < 2; ++di)
      av[di] = *(const short8*)(vt + ((di << 4) + lr) * LDP + (ks << 5) + (lg << 3));
    #pragma unroll
    for (int ni = 0; ni < 4; ++ni)
      pb[ni] = *(const short8*)(pl + ((ni << 4) + lr) * LDP + (ks << 5) + (lg << 3));
    #pragma unroll
    for (int di = 0; di < 2; ++di)
      #pragma unroll
      for (int ni = 0; ni < 4; ++ni)
        o[di][ni] = __builtin_amdgcn_mfma_f32_16x16x32_bf16(av[di], pb[ni], o[di][ni], 0, 0, 0);
  }
  __syncthreads();
  #pragma unroll
  for (int di = 0; di < 2; ++di)
    #pragma unroll
    for (int ni = 0; ni < 4; ++ni) {
      const int q = (ni << 4) + lr;
      short4v ov;
      #pragma unroll
      for (int r = 0; r < 4; ++r) ov[r] = f2bf(o[di][ni][r]);
      *(short4v*)(ostage + q * 128 + w * 32 + (di << 4) + (lg << 2)) = ov;
    }
  __syncthreads();
  const size_t obase = (yrow_base + (size_t)w_l * 64) * 256 + (size_t)blockIdx.y * 128;
  for (int cc = tid; cc < 64 * 16; cc += 256) {
    const int tok = cc >> 4, off = cc & 15;
    const short8 vv = *(const short8*)(ostage + tok * 128 + off * 8);
    *(short8*)(Yw + obase + (size_t)tok * 256 + off * 8) = vv;
  }
}

// ---------------- spectral attention (66 tokens) + in-LDS irfft ----------------
// One block per window; 4 waves handle heads {pass*4+w}; outF (66x256) in LDS;
// then per-column irfft and Yw += result.
__global__ __launch_bounds__(256)
void attn_spec(const short* __restrict__ QKV, short* __restrict__ Yw,
               const size_t yrow_base) {
  constexpr int NTOK = 66, NQP = 80, NKP = 96, LDP = 104;
  constexpr int FQ = 5, FK = 6, KS = 3;
  __shared__ short vt_s[4 * 32 * LDP];   // 13312
  __shared__ short pl_s[4 * NQP * LDP];  // 33280
  __shared__ short outF[66 * 256];       // 16896
  __shared__ float ct[64], st[64];
  const int tid = threadIdx.x;
  const int w = tid >> 6, l = tid & 63;
  const int lr = l & 15, lg = l >> 4;
  const int w_l = blockIdx.x;
  const size_t rowbase = (size_t)w_l * 130 + 64;
  short* vt = vt_s + w * 32 * LDP;
  short* pl = pl_s + w * NQP * LDP;
  if (tid < 64) {
    float ang = (float)tid * TWO_PI_64;
    ct[tid] = cosf(ang);
    st[tid] = sinf(ang);
  }
  for (int pass = 0; pass < 2; ++pass) {
    const int h = pass * 4 + w;
    #pragma unroll
    for (int i = 0; i < 6; ++i) {
      const int chunk = i * 64 + l;
      const int tok = chunk >> 2, d0 = (chunk & 3) << 3;
      short8 vv = {};
      if (tok < NTOK)
        vv = *(const short8*)(QKV + (rowbase + tok) * 768 + 512 + h * 32 + d0);
      #pragma unroll
      for (int j = 0; j < 8; ++j) vt[(d0 + j) * LDP + tok] = vv[j];
    }
    short8 bq[FQ], akf[FK];
    #pragma unroll
    for (int ni = 0; ni < FQ; ++ni) {
      const int q = (ni << 4) + lr;
      short8 z = {};
      bq[ni] = (q < NTOK)
        ? *(const short8*)(QKV + (rowbase + q) * 768 + h * 32 + (lg << 3)) : z;
    }
    #pragma unroll
    for (int mi = 0; mi < FK; ++mi) {
      const int mm = (mi << 4) + lr;
      short8 z = {};
      akf[mi] = (mm < NTOK)
        ? *(const short8*)(QKV + (rowbase + mm) * 768 + 256 + h * 32 + (lg << 3)) : z;
    }
    #pragma unroll
    for (int ni = 0; ni < FQ; ++ni) {
      f32x4 s[FK];
      #pragma unroll
      for (int mi = 0; mi < FK; ++mi) {
        f32x4 z = {};
        s[mi] = __builtin_amdgcn_mfma_f32_16x16x32_bf16(akf[mi], bq[ni], z, 0, 0, 0);
      }
      const int q = (ni << 4) + lr;
      float lv[FK][4];
      float mx = -3.0e30f;
      #pragma unroll
      for (int mi = 0; mi < FK; ++mi)
        #pragma unroll
        for (int r = 0; r < 4; ++r) {
          const int mm = (mi << 4) + (lg << 2) + r;
          float tt = s[mi][r] * ATT_SCALE;
          if (mm >= NTOK) tt = -3.0e30f;
          lv[mi][r] = tt;
          mx = fmaxf(mx, tt);
        }
      mx = fmaxf(mx, __shfl_xor(mx, 16));
      mx = fmaxf(mx, __shfl_xor(mx, 32));
      float sum = 0.f;
      #pragma unroll
      for (int mi = 0; mi < FK; ++mi)
        #pragma unroll
        for (int r = 0; r < 4; ++r) {
          const float p = __expf(lv[mi][r] - mx);
          lv[mi][r] = p;
          sum += p;
        }
      sum += __shfl_xor(sum, 16);
      sum += __shfl_xor(sum, 32);
      const float inv = 1.0f / sum;
      #pragma unroll
      for (int mi = 0; mi < FK; ++mi) {
        short4v pk;
        #pragma unroll
        for (int r = 0; r < 4; ++r) pk[r] = f2bf(lv[mi][r] * inv);
        *(short4v*)(pl + q * LDP + (mi << 4) + (lg << 2)) = pk;
      }
    }
    __syncthreads();
    f32x4 o[2][FQ] = {};
    #pragma unroll
    for (int ks = 0; ks < KS; ++ks) {
      short8 av[2], pb[FQ];
      #pragma unroll
      for (int di = 0; di < 2; ++di)
        av[di] = *(const short8*)(vt + ((di << 4) + lr) * LDP + (ks << 5) + (lg << 3));
      #pragma unroll
      for (int ni = 0; ni < FQ; ++ni)
        pb[ni] = *(const short8*)(pl + ((ni << 4) + lr) * LDP + (ks << 5) + (lg << 3));
      #pragma unroll
      for (int di = 0; di < 2; ++di)
        #pragma unroll
        for (int ni = 0; ni < FQ; ++ni)
          o[di][ni] = __builtin_amdgcn_mfma_f32_16x16x32_bf16(av[di], pb[ni], o[di][ni], 0, 0, 0);
    }
    #pragma unroll
    for (int di = 0; di < 2; ++di)
      #pragma unroll
      for (int ni = 0; ni < FQ; ++ni) {
        const int q = (ni << 4) + lr;
        if (q < NTOK) {
          short4v ov;
          #pragma unroll
          for (int r = 0; r < 4; ++r) ov[r] = f2bf(o[di][ni][r]);
          *(short4v*)(outF + q * 256 + h * 32 + (di << 4) + (lg << 2)) = ov;
        }
      }
    __syncthreads();
  }
  // irfft over tokens + combine into Yw (RMW; spatial part already written)
  const int c = tid;
  float rk[33], ik[33];
  #pragma unroll
  for (int k = 0; k <= 32; ++k) {
    rk[k] = bf2f(outF[k * 256 + c]);
    ik[k] = bf2f(outF[(k + 33) * 256 + c]);
  }
  const size_t ybase = (yrow_base + (size_t)w_l * 64) * 256 + c;
  for (int n = 0; n < 64; ++n) {
    float acc = rk[0];
    int m = 0;
    #pragma unroll
    for (int k = 1; k <= 32; ++k) {
      m = (m + n) & 63;
      const float wk = (k == 32) ? 1.f : 2.f;
      acc += wk * (ct[m] * rk[k] - st[m] * ik[k]);
    }
    const size_t idx = ybase + (size_t)n * 256;
    Yw[idx] = f2bf(bf2f(Yw[idx]) + acc * 0.125f);
  }
}

// ---------------- LN2 ----------------
__global__ __launch_bounds__(256)
void k_ln2(const float* __restrict__ xin, const float* __restrict__ nw,
           const float* __restrict__ nb, short* __restrict__ t2) {
  __shared__ float wS[256], bS[256];
  const int tid = threadIdx.x;
  wS[tid] = nw[tid];
  bS[tid] = nb[tid];
  __syncthreads();
  const int g = tid >> 4, l16 = tid & 15;
  const size_t row = (size_t)blockIdx.x * 16 + g;
  const float4* xv4 = (const float4*)(xin + row * 256);
  float4 v[4];
  float s = 0.f, ss = 0.f;
  #pragma unroll
  for (int j = 0; j < 4; ++j) {
    v[j] = xv4[l16 * 4 + j];
    s  += v[j].x + v[j].y + v[j].z + v[j].w;
    ss += v[j].x * v[j].x + v[j].y * v[j].y + v[j].z * v[j].z + v[j].w * v[j].w;
  }
  #pragma unroll
  for (int m = 1; m < 16; m <<= 1) {
    s  += __shfl_xor(s, m);
    ss += __shfl_xor(ss, m);
  }
  const float mean = s * 0.00390625f;
  const float var  = ss * 0.00390625f - mean * mean;
  const float rs   = rsqrtf(var + 1e-5f);
  short tmp[16];
  #pragma unroll
  for (int j = 0; j < 4; ++j) {
    const float* vp = (const float*)&v[j];
    #pragma unroll
    for (int e = 0; e < 4; ++e) {
      const int c0 = l16 * 16 + j * 4 + e;
      tmp[j * 4 + e] = f2bf((vp[e] - mean) * rs * wS[c0] + bS[c0]);
    }
  }
  short8* dg = (short8*)(t2 + row * 256 + l16 * 16);
  dg[0] = ((short8*)tmp)[0];
  dg[1] = ((short8*)tmp)[1];
}

extern "C" void kernel_launch(void* const* d_in, const int* in_sizes, int n_in,
                              void* d_out, int out_size, void* d_ws, size_t ws_size,
                              hipStream_t stream) {
  const float* x    = (const float*)d_in[0];
  const float* n1w  = (const float*)d_in[2];
  const float* n1b  = (const float*)d_in[3];
  const float* qkvw = (const float*)d_in[4];
  const float* qkvb = (const float*)d_in[5];
  const float* rpb  = (const float*)d_in[6];
  const float* prw  = (const float*)d_in[7];
  const float* prb  = (const float*)d_in[8];
  const float* n2w  = (const float*)d_in[9];
  const float* n2b  = (const float*)d_in[10];
  const float* f1w  = (const float*)d_in[11];
  const float* f1b  = (const float*)d_in[12];
  const float* f2w  = (const float*)d_in[13];
  const float* f2b  = (const float*)d_in[14];
  float* out = (float*)d_out;
  char* ws = (char*)d_ws;

  // layout (peak 270,008,320 B)
  short* T    = (short*)(ws);                       // 136,314,880
  short* QKVc = (short*)(ws + 136314880ULL);        // 51,118,080 (chunk)
  short* Yw   = (short*)(ws + 187432960ULL);        // 67,108,864
  float* X2   = (float*)(ws);                       // 134,217,728 (over dead T)
  short* T2   = (short*)(ws + 134217728ULL);        // 67,108,864
  short* HIDq = (short*)(ws + 201326592ULL);        // 67,108,864
  short* WB   = (short*)(ws + 268435456ULL);        // 1,572,864

  const short* QKV_WB = WB;
  const short* PR_WB  = WB + 196608;
  const short* F1_WB  = WB + 262144;
  const short* F2_WB  = WB + 524288;

  k_wconv<<<dim3(3072), dim3(256), 0, stream>>>(qkvw, prw, f1w, f2w, WB);
  k_ln1_fft<<<dim3(2048), dim3(256), 0, stream>>>(x, n1w, n1b, T);

  for (int c = 0; c < 8; ++c) {
    const short* Tc = T + (size_t)c * 33280 * 256;
    gemm128<0><<<dim3(6, 260), dim3(256), 0, stream>>>(
        Tc, QKV_WB, qkvb, nullptr, QKVc, nullptr, 768, 256, 256, 256);
    attn_spatial<<<dim3(256, 2), dim3(256), 0, stream>>>(
        QKVc, rpb, Yw, (size_t)c * 16384);
    attn_spec<<<dim3(256), dim3(256), 0, stream>>>(
        QKVc, Yw, (size_t)c * 16384);
  }

  gemm128<1><<<dim3(2, 1024), dim3(256), 0, stream>>>(
      Yw, PR_WB, prb, x, nullptr, X2, 256, 256, 256, 256);
  k_ln2<<<dim3(8192), dim3(256), 0, stream>>>(X2, n2w, n2b, T2);

  for (int p = 0; p < 4; ++p) {
    gemm128<2><<<dim3(2, 1024), dim3(256), 0, stream>>>(
        T2, F1_WB + p * 65536, f1b + p * 256, nullptr, HIDq, nullptr, 256, 256, 256, 256);
    if (p == 0) {
      gemm128<3><<<dim3(2, 1024), dim3(256), 0, stream>>>(
          HIDq, F2_WB + p * 256, f2b, X2, nullptr, out, 256, 256, 256, 1024);
    } else {
      gemm128<4><<<dim3(2, 1024), dim3(256), 0, stream>>>(
          HIDq, F2_WB + p * 256, f2b, X2, nullptr, out, 256, 256, 256, 1024);
    }
  }

  (void)in_sizes; (void)n_in; (void)out_size; (void)ws_size;
}

// Round 3
// 1905.718 us; speedup vs baseline: 1.0992x; 1.0992x over previous
//
#include <hip/hip_runtime.h>
#include <stdint.h>
#include <math.h>

// EncoderTransformerBlock (Swin-like, 8x8 windows, C=256, heads=8) on gfx950.
// v3: rfft folded past the QKV GEMM (DFT commutes with channel mixing).
//  k_wconv     : fp32 weights -> bf16
//  k_ln1       : LN1 + window partition -> T (131072x256 bf16, 64 rows/window)
//  per chunk c (4 chunks of 512 windows):
//    gemm128<0>: qkv spatial = T_chunk @ qkv_w^T + b -> QKVc rows win*130+{0..63}
//    k_dft     : spectral qkv rows = F(66x64) @ qkv_spatial (MFMA) + bias fix
//                -> QKVc rows win*130+{64..129}
//    attn_spatial / attn_spec (+in-LDS irfft) -> Yw
//  gemm128<1>  : X2 = Yw @ proj_w^T + b + x  (raster scatter, fp32)
//  k_ln2       : T2 = LN2(X2) bf16
//  4x passes   : gemm128<2> HIDq=gelu(T2@fc1[p]^T+b); gemm128<3|4> out (=|+=)
// Workspace peak 270,008,320 B (same as proven v2 layout).

using short8  = __attribute__((ext_vector_type(8))) short;
using short4v = __attribute__((ext_vector_type(4))) short;
using f32x4   = __attribute__((ext_vector_type(4))) float;

#define DEV __device__ __forceinline__

static constexpr float ATT_SCALE = 0.17677669529663688f;   // 32^-0.5
static constexpr float TWO_PI_64 = 0.09817477042468103f;   // 2*pi/64

DEV short f2bf(float f) {
  union { float f; uint32_t u; } x; x.f = f;
  uint32_t u = x.u;
  uint32_t r = u + 0x7fffu + ((u >> 16) & 1u);
  if ((u & 0x7f800000u) == 0x7f800000u) r = u;
  return (short)(r >> 16);
}
DEV float bf2f(short s) {
  union { uint32_t u; float f; } x;
  x.u = ((uint32_t)(uint16_t)s) << 16;
  return x.f;
}

DEV void llds16(const void* g, void* lds) {
  __builtin_amdgcn_global_load_lds(
      (const __attribute__((address_space(1))) uint32_t*)g,
      (__attribute__((address_space(3))) uint32_t*)lds, 16, 0, 0);
}

// ---------------- weight fp32->bf16 ----------------
__global__ __launch_bounds__(256)
void k_wconv(const float* __restrict__ qw, const float* __restrict__ pw,
             const float* __restrict__ f1, const float* __restrict__ f2,
             short* __restrict__ o) {
  const int i = blockIdx.x * 256 + threadIdx.x;
  float v;
  if (i < 196608) v = qw[i];
  else if (i < 262144) v = pw[i - 196608];
  else if (i < 524288) v = f1[i - 262144];
  else v = f2[i - 524288];
  o[i] = f2bf(v);
}

// ---------------- LN1 + window partition (no FFT) ----------------
__global__ __launch_bounds__(256)
void k_ln1(const float* __restrict__ x, const float* __restrict__ nw,
           const float* __restrict__ nb, short* __restrict__ T) {
  __shared__ float wS[256], bS[256];
  const int tid = threadIdx.x;
  const int wdw = blockIdx.x;
  const int bb = wdw >> 10, rem = wdw & 1023, wy = rem >> 5, wx = rem & 31;
  wS[tid] = nw[tid];
  bS[tid] = nb[tid];
  __syncthreads();
  const int g = tid >> 4, l16 = tid & 15;
  #pragma unroll
  for (int it = 0; it < 4; ++it) {
    const int t = it * 16 + g;
    const int gy = (wy << 3) + (t >> 3), gx = (wx << 3) + (t & 7);
    const size_t rrow = ((size_t)bb * 256 + gy) * 256 + gx;
    const float4* xv4 = (const float4*)(x + rrow * 256);
    float4 v[4];
    float s = 0.f, ss = 0.f;
    #pragma unroll
    for (int j = 0; j < 4; ++j) {
      v[j] = xv4[l16 * 4 + j];
      s  += v[j].x + v[j].y + v[j].z + v[j].w;
      ss += v[j].x * v[j].x + v[j].y * v[j].y + v[j].z * v[j].z + v[j].w * v[j].w;
    }
    #pragma unroll
    for (int m = 1; m < 16; m <<= 1) {
      s  += __shfl_xor(s, m);
      ss += __shfl_xor(ss, m);
    }
    const float mean = s * 0.00390625f;
    const float var  = ss * 0.00390625f - mean * mean;
    const float rs   = rsqrtf(var + 1e-5f);
    short tmp[16];
    #pragma unroll
    for (int j = 0; j < 4; ++j) {
      const float* vp = (const float*)&v[j];
      #pragma unroll
      for (int e = 0; e < 4; ++e) {
        const int c0 = l16 * 16 + j * 4 + e;
        tmp[j * 4 + e] = f2bf((vp[e] - mean) * rs * wS[c0] + bS[c0]);
      }
    }
    short8* dg = (short8*)(T + ((size_t)wdw * 64 + t) * 256 + l16 * 16);
    dg[0] = ((short8*)tmp)[0];
    dg[1] = ((short8*)tmp)[1];
  }
}

// ---------------- DFT of qkv rows via MFMA ----------------
// grid (6 col-tiles, nwin). Yf(80x128) = F(80x64) @ qkv_spatial(64x128),
// write rows 0..65 to QKVc rows win*130+64+{0..65} with bias correction:
// row 0: -7*b, rows>=1: +b (since qkv already contains +b and F@1 = [8,0..]).
__global__ __launch_bounds__(256)
void k_dft(short* __restrict__ QKV, const float* __restrict__ qkvb) {
  __shared__ short F[80 * 72];
  __shared__ short sbuf[10880];   // Xt[128][72] then yf[80][136]
  const int tid = threadIdx.x;
  const int w = tid >> 6, l = tid & 63;
  const int lr = l & 15, lg = l >> 4;
  const int wdw = blockIdx.y, ct = blockIdx.x;
  const size_t base = (size_t)wdw * 130;
  for (int i = tid; i < 80 * 64; i += 256) {
    const int row = i >> 6, n = i & 63;
    float v = 0.f;
    if (row < 33) v = 0.125f * cosf((float)((row * n) & 63) * TWO_PI_64);
    else if (row < 66) v = -0.125f * sinf((float)(((row - 33) * n) & 63) * TWO_PI_64);
    F[row * 72 + n] = f2bf(v);
  }
  short* Xt = sbuf;
  #pragma unroll
  for (int i = 0; i < 4; ++i) {
    const int cc = i * 256 + tid;
    const int tok = cc >> 4, c8 = cc & 15;
    const short8 v = *(const short8*)(QKV + (base + tok) * 768 + ct * 128 + c8 * 8);
    const int sw = (c8 & 3) << 3;
    #pragma unroll
    for (int j = 0; j < 8; ++j)
      Xt[(c8 * 8 + j) * 72 + (tok ^ sw)] = v[j];
  }
  __syncthreads();
  const int wcol = w << 5;
  f32x4 acc[5][2] = {};
  #pragma unroll
  for (int kk = 0; kk < 2; ++kk) {
    short8 af[5], bfr[2];
    #pragma unroll
    for (int mi = 0; mi < 5; ++mi)
      af[mi] = *(const short8*)(F + ((mi << 4) + lr) * 72 + (kk << 5) + (lg << 3));
    #pragma unroll
    for (int ni = 0; ni < 2; ++ni) {
      const int col = wcol + (ni << 4) + lr;
      const int sw = ((col >> 3) & 3) << 3;
      bfr[ni] = *(const short8*)(Xt + col * 72 + (((kk << 5) + (lg << 3)) ^ sw));
    }
    #pragma unroll
    for (int mi = 0; mi < 5; ++mi)
      #pragma unroll
      for (int ni = 0; ni < 2; ++ni)
        acc[mi][ni] = __builtin_amdgcn_mfma_f32_16x16x32_bf16(af[mi], bfr[ni], acc[mi][ni], 0, 0, 0);
  }
  __syncthreads();
  short* yf = sbuf;
  #pragma unroll
  for (int mi = 0; mi < 5; ++mi)
    #pragma unroll
    for (int ni = 0; ni < 2; ++ni)
      #pragma unroll
      for (int r = 0; r < 4; ++r)
        yf[((mi << 4) + (lg << 2) + r) * 136 + wcol + (ni << 4) + lr] = f2bf(acc[mi][ni][r]);
  __syncthreads();
  for (int cc = tid; cc < 66 * 16; cc += 256) {
    const int tok = cc >> 4, off = cc & 15;
    const short8 v = *(const short8*)(yf + tok * 136 + off * 8);
    const float bs = (tok == 0) ? -7.f : 1.f;
    short8 o;
    #pragma unroll
    for (int j = 0; j < 8; ++j)
      o[j] = f2bf(bf2f(v[j]) + bs * qkvb[ct * 128 + off * 8 + j]);
    *(short8*)(QKV + (base + 64 + tok) * 768 + ct * 128 + off * 8) = o;
  }
}

// ---------------- 128x128 MFMA GEMM (global_load_lds staging) ----------------
// EPI: 0 +bias->bf16 qkv (row remap win*130+tok) | 1 +bias+x raster ->f32
//      2 +bias,gelu->bf16 | 3 +bias+addf->f32 | 4 out += val
template<int EPI>
__global__ __launch_bounds__(256)
void gemm128(const short* __restrict__ A, const short* __restrict__ Bt,
             const float* __restrict__ bias, const float* __restrict__ addf,
             short* __restrict__ outb, float* __restrict__ outf,
             const int N, const int K, const int lda, const int ldb) {
  __shared__ short As[128 * 32];
  __shared__ short Bs[128 * 32];
  const int tid = threadIdx.x;
  const int w = tid >> 6, l = tid & 63;
  const int lr = l & 15, lg = l >> 4;
  const int bm = blockIdx.y << 7, bn = blockIdx.x << 7;
  const int wm = (w >> 1) << 6, wn = (w & 1) << 6;
  f32x4 acc[4][4] = {};
  const int rloc = l >> 2, kc = (l & 3) << 3;
  for (int kt = 0; kt < K; kt += 32) {
    #pragma unroll
    for (int i = 0; i < 2; ++i) {
      const int seg = i * 4 + w;
      const int row = (seg << 4) + rloc;
      llds16(A  + (size_t)(bm + row) * lda + kt + kc, As + seg * 512);
      llds16(Bt + (size_t)(bn + row) * ldb + kt + kc, Bs + seg * 512);
    }
    __syncthreads();
    short8 af[4], bfr[4];
    #pragma unroll
    for (int mi = 0; mi < 4; ++mi)
      af[mi] = *(const short8*)(As + ((wm + (mi << 4) + lr) << 5) + (lg << 3));
    #pragma unroll
    for (int ni = 0; ni < 4; ++ni)
      bfr[ni] = *(const short8*)(Bs + ((wn + (ni << 4) + lr) << 5) + (lg << 3));
    #pragma unroll
    for (int mi = 0; mi < 4; ++mi)
      #pragma unroll
      for (int ni = 0; ni < 4; ++ni)
        acc[mi][ni] = __builtin_amdgcn_mfma_f32_16x16x32_bf16(af[mi], bfr[ni], acc[mi][ni], 0, 0, 0);
    __syncthreads();
  }
  #pragma unroll
  for (int mi = 0; mi < 4; ++mi) {
    #pragma unroll
    for (int ni = 0; ni < 4; ++ni) {
      const f32x4 v = acc[mi][ni];
      const int col = bn + wn + (ni << 4) + lr;
      const int row0 = bm + wm + (mi << 4) + (lg << 2);
      const float bc = (EPI == 4) ? 0.f : bias[col];
      #pragma unroll
      for (int r = 0; r < 4; ++r) {
        const int row = row0 + r;
        float val = v[r] + bc;
        if (EPI == 0) {
          const size_t orow = (size_t)((row >> 6) * 130) + (row & 63);
          outb[orow * N + col] = f2bf(val);
        } else if (EPI == 2) {
          float gl = 0.5f * val * (1.0f + erff(val * 0.7071067811865475f));
          outb[(size_t)row * N + col] = f2bf(gl);
        } else if (EPI == 1) {
          const int ww = row >> 6, t = row & 63;
          const int b2 = ww >> 10, rem = ww & 1023;
          const int gy = ((rem >> 5) << 3) + (t >> 3);
          const int gx = ((rem & 31) << 3) + (t & 7);
          const size_t rr = ((size_t)b2 * 256 + gy) * 256 + gx;
          outf[rr * 256 + col] = val + addf[rr * 256 + col];
        } else if (EPI == 3) {
          outf[(size_t)row * N + col] = val + addf[(size_t)row * N + col];
        } else {
          outf[(size_t)row * N + col] += val;
        }
      }
    }
  }
}

// ---------------- spatial window attention (4 waves = 4 heads) ----------------
__global__ __launch_bounds__(256)
void attn_spatial(const short* __restrict__ QKV, const float* __restrict__ rpb,
                  short* __restrict__ Yw, const size_t yrow_base) {
  constexpr int LDP = 72;
  __shared__ short vt_s[4 * 32 * LDP];
  __shared__ short pl_s[4 * 64 * LDP];
  const int tid = threadIdx.x;
  const int w = tid >> 6, l = tid & 63;
  const int lr = l & 15, lg = l >> 4;
  const int w_l = blockIdx.x;
  const int h = blockIdx.y * 4 + w;
  const size_t rowbase = (size_t)w_l * 130;
  short* vt = vt_s + w * 32 * LDP;
  short* pl = pl_s + w * 64 * LDP;
  short* ostage = pl_s;

  #pragma unroll
  for (int i = 0; i < 4; ++i) {
    const int chunk = i * 64 + l;
    const int tok = chunk >> 2, d0 = (chunk & 3) << 3;
    const short8 vv = *(const short8*)(QKV + (rowbase + tok) * 768 + 512 + h * 32 + d0);
    #pragma unroll
    for (int j = 0; j < 8; ++j) vt[(d0 + j) * LDP + tok] = vv[j];
  }
  short8 bq[4], akf[4];
  #pragma unroll
  for (int ni = 0; ni < 4; ++ni)
    bq[ni] = *(const short8*)(QKV + (rowbase + (ni << 4) + lr) * 768 + h * 32 + (lg << 3));
  #pragma unroll
  for (int mi = 0; mi < 4; ++mi)
    akf[mi] = *(const short8*)(QKV + (rowbase + (mi << 4) + lr) * 768 + 256 + h * 32 + (lg << 3));

  #pragma unroll
  for (int ni = 0; ni < 4; ++ni) {
    f32x4 s[4];
    #pragma unroll
    for (int mi = 0; mi < 4; ++mi) {
      f32x4 z = {};
      s[mi] = __builtin_amdgcn_mfma_f32_16x16x32_bf16(akf[mi], bq[ni], z, 0, 0, 0);
    }
    const int q = (ni << 4) + lr;
    float lv[4][4];
    float mx = -3.0e30f;
    #pragma unroll
    for (int mi = 0; mi < 4; ++mi) {
      #pragma unroll
      for (int r = 0; r < 4; ++r) {
        const int mm = (mi << 4) + (lg << 2) + r;
        const int dy = (q >> 3) - (mm >> 3) + 7;
        const int dx = (q & 7) - (mm & 7) + 7;
        float tt = s[mi][r] * ATT_SCALE + rpb[(dy * 15 + dx) * 8 + h];
        lv[mi][r] = tt;
        mx = fmaxf(mx, tt);
      }
    }
    mx = fmaxf(mx, __shfl_xor(mx, 16));
    mx = fmaxf(mx, __shfl_xor(mx, 32));
    float sum = 0.f;
    #pragma unroll
    for (int mi = 0; mi < 4; ++mi)
      #pragma unroll
      for (int r = 0; r < 4; ++r) {
        const float p = __expf(lv[mi][r] - mx);
        lv[mi][r] = p;
        sum += p;
      }
    sum += __shfl_xor(sum, 16);
    sum += __shfl_xor(sum, 32);
    const float inv = 1.0f / sum;
    #pragma unroll
    for (int mi = 0; mi < 4; ++mi) {
      short4v pk;
      #pragma unroll
      for (int r = 0; r < 4; ++r) pk[r] = f2bf(lv[mi][r] * inv);
      *(short4v*)(pl + q * LDP + (mi << 4) + (lg << 2)) = pk;
    }
  }
  __syncthreads();

  f32x4 o[2][4] = {};
  #pragma unroll
  for (int ks = 0; ks < 2; ++ks) {
    short8 av[2], pb[4];
    #pragma unroll
    for (int di = 0; di < 2; ++di)
      av[di] = *(const short8*)(vt + ((di << 4) + lr) * LDP + (ks << 5) + (lg << 3));
    #pragma unroll
    for (int ni = 0; ni < 4; ++ni)
      pb[ni] = *(const short8*)(pl + ((ni << 4) + lr) * LDP + (ks << 5) + (lg << 3));
    #pragma unroll
    for (int di = 0; di < 2; ++di)
      #pragma unroll
      for (int ni = 0; ni < 4; ++ni)
        o[di][ni] = __builtin_amdgcn_mfma_f32_16x16x32_bf16(av[di], pb[ni], o[di][ni], 0, 0, 0);
  }
  __syncthreads();
  #pragma unroll
  for (int di = 0; di < 2; ++di)
    #pragma unroll
    for (int ni = 0; ni < 4; ++ni) {
      const int q = (ni << 4) + lr;
      short4v ov;
      #pragma unroll
      for (int r = 0; r < 4; ++r) ov[r] = f2bf(o[di][ni][r]);
      *(short4v*)(ostage + q * 128 + w * 32 + (di << 4) + (lg << 2)) = ov;
    }
  __syncthreads();
  const size_t obase = (yrow_base + (size_t)w_l * 64) * 256 + (size_t)blockIdx.y * 128;
  for (int cc = tid; cc < 64 * 16; cc += 256) {
    const int tok = cc >> 4, off = cc & 15;
    const short8 vv = *(const short8*)(ostage + tok * 128 + off * 8);
    *(short8*)(Yw + obase + (size_t)tok * 256 + off * 8) = vv;
  }
}

// ---------------- spectral attention (66 tokens) + in-LDS irfft ----------------
__global__ __launch_bounds__(256)
void attn_spec(const short* __restrict__ QKV, short* __restrict__ Yw,
               const size_t yrow_base) {
  constexpr int NTOK = 66, NQP = 80, LDP = 104;
  constexpr int FQ = 5, FK = 6, KS = 3;
  __shared__ short vt_s[4 * 32 * LDP];
  __shared__ short pl_s[4 * NQP * LDP];
  __shared__ short outF[66 * 256];
  __shared__ float ct[64], st[64];
  const int tid = threadIdx.x;
  const int w = tid >> 6, l = tid & 63;
  const int lr = l & 15, lg = l >> 4;
  const int w_l = blockIdx.x;
  const size_t rowbase = (size_t)w_l * 130 + 64;
  short* vt = vt_s + w * 32 * LDP;
  short* pl = pl_s + w * NQP * LDP;
  if (tid < 64) {
    float ang = (float)tid * TWO_PI_64;
    ct[tid] = cosf(ang);
    st[tid] = sinf(ang);
  }
  for (int pass = 0; pass < 2; ++pass) {
    const int h = pass * 4 + w;
    #pragma unroll
    for (int i = 0; i < 6; ++i) {
      const int chunk = i * 64 + l;
      const int tok = chunk >> 2, d0 = (chunk & 3) << 3;
      short8 vv = {};
      if (tok < NTOK)
        vv = *(const short8*)(QKV + (rowbase + tok) * 768 + 512 + h * 32 + d0);
      #pragma unroll
      for (int j = 0; j < 8; ++j) vt[(d0 + j) * LDP + tok] = vv[j];
    }
    short8 bq[FQ], akf[FK];
    #pragma unroll
    for (int ni = 0; ni < FQ; ++ni) {
      const int q = (ni << 4) + lr;
      short8 z = {};
      bq[ni] = (q < NTOK)
        ? *(const short8*)(QKV + (rowbase + q) * 768 + h * 32 + (lg << 3)) : z;
    }
    #pragma unroll
    for (int mi = 0; mi < FK; ++mi) {
      const int mm = (mi << 4) + lr;
      short8 z = {};
      akf[mi] = (mm < NTOK)
        ? *(const short8*)(QKV + (rowbase + mm) * 768 + 256 + h * 32 + (lg << 3)) : z;
    }
    #pragma unroll
    for (int ni = 0; ni < FQ; ++ni) {
      f32x4 s[FK];
      #pragma unroll
      for (int mi = 0; mi < FK; ++mi) {
        f32x4 z = {};
        s[mi] = __builtin_amdgcn_mfma_f32_16x16x32_bf16(akf[mi], bq[ni], z, 0, 0, 0);
      }
      const int q = (ni << 4) + lr;
      float lv[FK][4];
      float mx = -3.0e30f;
      #pragma unroll
      for (int mi = 0; mi < FK; ++mi)
        #pragma unroll
        for (int r = 0; r < 4; ++r) {
          const int mm = (mi << 4) + (lg << 2) + r;
          float tt = s[mi][r] * ATT_SCALE;
          if (mm >= NTOK) tt = -3.0e30f;
          lv[mi][r] = tt;
          mx = fmaxf(mx, tt);
        }
      mx = fmaxf(mx, __shfl_xor(mx, 16));
      mx = fmaxf(mx, __shfl_xor(mx, 32));
      float sum = 0.f;
      #pragma unroll
      for (int mi = 0; mi < FK; ++mi)
        #pragma unroll
        for (int r = 0; r < 4; ++r) {
          const float p = __expf(lv[mi][r] - mx);
          lv[mi][r] = p;
          sum += p;
        }
      sum += __shfl_xor(sum, 16);
      sum += __shfl_xor(sum, 32);
      const float inv = 1.0f / sum;
      #pragma unroll
      for (int mi = 0; mi < FK; ++mi) {
        short4v pk;
        #pragma unroll
        for (int r = 0; r < 4; ++r) pk[r] = f2bf(lv[mi][r] * inv);
        *(short4v*)(pl + q * LDP + (mi << 4) + (lg << 2)) = pk;
      }
    }
    __syncthreads();
    f32x4 o[2][FQ] = {};
    #pragma unroll
    for (int ks = 0; ks < KS; ++ks) {
      short8 av[2], pb[FQ];
      #pragma unroll
      for (int di = 0; di < 2; ++di)
        av[di] = *(const short8*)(vt + ((di << 4) + lr) * LDP + (ks << 5) + (lg << 3));
      #pragma unroll
      for (int ni = 0; ni < FQ; ++ni)
        pb[ni] = *(const short8*)(pl + ((ni << 4) + lr) * LDP + (ks << 5) + (lg << 3));
      #pragma unroll
      for (int di = 0; di < 2; ++di)
        #pragma unroll
        for (int ni = 0; ni < FQ; ++ni)
          o[di][ni] = __builtin_amdgcn_mfma_f32_16x16x32_bf16(av[di], pb[ni], o[di][ni], 0, 0, 0);
    }
    #pragma unroll
    for (int di = 0; di < 2; ++di)
      #pragma unroll
      for (int ni = 0; ni < FQ; ++ni) {
        const int q = (ni << 4) + lr;
        if (q < NTOK) {
          short4v ov;
          #pragma unroll
          for (int r = 0; r < 4; ++r) ov[r] = f2bf(o[di][ni][r]);
          *(short4v*)(outF + q * 256 + h * 32 + (di << 4) + (lg << 2)) = ov;
        }
      }
    __syncthreads();
  }
  const int c = tid;
  float rk[33], ik[33];
  #pragma unroll
  for (int k = 0; k <= 32; ++k) {
    rk[k] = bf2f(outF[k * 256 + c]);
    ik[k] = bf2f(outF[(k + 33) * 256 + c]);
  }
  const size_t ybase = (yrow_base + (size_t)w_l * 64) * 256 + c;
  for (int n = 0; n < 64; ++n) {
    float acc = rk[0];
    int m = 0;
    #pragma unroll
    for (int k = 1; k <= 32; ++k) {
      m = (m + n) & 63;
      const float wk = (k == 32) ? 1.f : 2.f;
      acc += wk * (ct[m] * rk[k] - st[m] * ik[k]);
    }
    const size_t idx = ybase + (size_t)n * 256;
    Yw[idx] = f2bf(bf2f(Yw[idx]) + acc * 0.125f);
  }
}

// ---------------- LN2 ----------------
__global__ __launch_bounds__(256)
void k_ln2(const float* __restrict__ xin, const float* __restrict__ nw,
           const float* __restrict__ nb, short* __restrict__ t2) {
  __shared__ float wS[256], bS[256];
  const int tid = threadIdx.x;
  wS[tid] = nw[tid];
  bS[tid] = nb[tid];
  __syncthreads();
  const int g = tid >> 4, l16 = tid & 15;
  const size_t row = (size_t)blockIdx.x * 16 + g;
  const float4* xv4 = (const float4*)(xin + row * 256);
  float4 v[4];
  float s = 0.f, ss = 0.f;
  #pragma unroll
  for (int j = 0; j < 4; ++j) {
    v[j] = xv4[l16 * 4 + j];
    s  += v[j].x + v[j].y + v[j].z + v[j].w;
    ss += v[j].x * v[j].x + v[j].y * v[j].y + v[j].z * v[j].z + v[j].w * v[j].w;
  }
  #pragma unroll
  for (int m = 1; m < 16; m <<= 1) {
    s  += __shfl_xor(s, m);
    ss += __shfl_xor(ss, m);
  }
  const float mean = s * 0.00390625f;
  const float var  = ss * 0.00390625f - mean * mean;
  const float rs   = rsqrtf(var + 1e-5f);
  short tmp[16];
  #pragma unroll
  for (int j = 0; j < 4; ++j) {
    const float* vp = (const float*)&v[j];
    #pragma unroll
    for (int e = 0; e < 4; ++e) {
      const int c0 = l16 * 16 + j * 4 + e;
      tmp[j * 4 + e] = f2bf((vp[e] - mean) * rs * wS[c0] + bS[c0]);
    }
  }
  short8* dg = (short8*)(t2 + row * 256 + l16 * 16);
  dg[0] = ((short8*)tmp)[0];
  dg[1] = ((short8*)tmp)[1];
}

extern "C" void kernel_launch(void* const* d_in, const int* in_sizes, int n_in,
                              void* d_out, int out_size, void* d_ws, size_t ws_size,
                              hipStream_t stream) {
  const float* x    = (const float*)d_in[0];
  const float* n1w  = (const float*)d_in[2];
  const float* n1b  = (const float*)d_in[3];
  const float* qkvw = (const float*)d_in[4];
  const float* qkvb = (const float*)d_in[5];
  const float* rpb  = (const float*)d_in[6];
  const float* prw  = (const float*)d_in[7];
  const float* prb  = (const float*)d_in[8];
  const float* n2w  = (const float*)d_in[9];
  const float* n2b  = (const float*)d_in[10];
  const float* f1w  = (const float*)d_in[11];
  const float* f1b  = (const float*)d_in[12];
  const float* f2w  = (const float*)d_in[13];
  const float* f2b  = (const float*)d_in[14];
  float* out = (float*)d_out;
  char* ws = (char*)d_ws;

  // layout (peak 270,008,320 B)
  short* T    = (short*)(ws);                       // 67,108,864
  short* QKVc = (short*)(ws + 67108864ULL);         // 102,236,160 (512-window chunk)
  short* Yw   = (short*)(ws + 169345024ULL);        // 67,108,864
  float* X2   = (float*)(ws);                       // 134,217,728 (over dead T+QKVc head)
  short* T2   = (short*)(ws + 134217728ULL);        // 67,108,864
  short* HIDq = (short*)(ws + 201326592ULL);        // 67,108,864
  short* WB   = (short*)(ws + 268435456ULL);        // 1,572,864

  const short* QKV_WB = WB;
  const short* PR_WB  = WB + 196608;
  const short* F1_WB  = WB + 262144;
  const short* F2_WB  = WB + 524288;

  k_wconv<<<dim3(3072), dim3(256), 0, stream>>>(qkvw, prw, f1w, f2w, WB);
  k_ln1<<<dim3(2048), dim3(256), 0, stream>>>(x, n1w, n1b, T);

  for (int c = 0; c < 4; ++c) {
    const short* Tc = T + (size_t)c * 32768 * 256;
    gemm128<0><<<dim3(6, 256), dim3(256), 0, stream>>>(
        Tc, QKV_WB, qkvb, nullptr, QKVc, nullptr, 768, 256, 256, 256);
    k_dft<<<dim3(6, 512), dim3(256), 0, stream>>>(QKVc, qkvb);
    attn_spatial<<<dim3(512, 2), dim3(256), 0, stream>>>(
        QKVc, rpb, Yw, (size_t)c * 32768);
    attn_spec<<<dim3(512), dim3(256), 0, stream>>>(
        QKVc, Yw, (size_t)c * 32768);
  }

  gemm128<1><<<dim3(2, 1024), dim3(256), 0, stream>>>(
      Yw, PR_WB, prb, x, nullptr, X2, 256, 256, 256, 256);
  k_ln2<<<dim3(8192), dim3(256), 0, stream>>>(X2, n2w, n2b, T2);

  for (int p = 0; p < 4; ++p) {
    gemm128<2><<<dim3(2, 1024), dim3(256), 0, stream>>>(
        T2, F1_WB + p * 65536, f1b + p * 256, nullptr, HIDq, nullptr, 256, 256, 256, 256);
    if (p == 0) {
      gemm128<3><<<dim3(2, 1024), dim3(256), 0, stream>>>(
          HIDq, F2_WB + p * 256, f2b, X2, nullptr, out, 256, 256, 256, 1024);
    } else {
      gemm128<4><<<dim3(2, 1024), dim3(256), 0, stream>>>(
          HIDq, F2_WB + p * 256, f2b, X2, nullptr, out, 256, 256, 256, 1024);
    }
  }

  (void)in_sizes; (void)n_in; (void)out_size; (void)ws_size;
}

// Round 5
// 1515.396 us; speedup vs baseline: 1.3823x; 1.2576x over previous
//
#include <hip/hip_runtime.h>
#include <stdint.h>
#include <math.h>

// EncoderTransformerBlock (Swin-like, 8x8 windows, C=256, heads=8) on gfx950.
// v4 (resubmit; round-4 bench was an infra timeout): attn_spec irfft done as a
// second MFMA stage (Y^T = (PV)^T @ G^T), G generated in registers; coalesced
// LDS-staged RMW of Yw.
// Pipeline otherwise identical to v3 (passed, 1906us):
//  k_wconv, k_ln1, per-chunk {gemm128<0> qkv, k_dft, attn_spatial, attn_spec},
//  gemm128<1> proj+shortcut, k_ln2, 4x {gemm128<2> fc1+gelu, gemm128<3|4> fc2}.
// Workspace peak 270,008,320 B (proven).

using short8  = __attribute__((ext_vector_type(8))) short;
using short4v = __attribute__((ext_vector_type(4))) short;
using f32x4   = __attribute__((ext_vector_type(4))) float;

#define DEV __device__ __forceinline__

static constexpr float ATT_SCALE = 0.17677669529663688f;   // 32^-0.5
static constexpr float TWO_PI_64 = 0.09817477042468103f;   // 2*pi/64

DEV short f2bf(float f) {
  union { float f; uint32_t u; } x; x.f = f;
  uint32_t u = x.u;
  uint32_t r = u + 0x7fffu + ((u >> 16) & 1u);
  if ((u & 0x7f800000u) == 0x7f800000u) r = u;
  return (short)(r >> 16);
}
DEV float bf2f(short s) {
  union { uint32_t u; float f; } x;
  x.u = ((uint32_t)(uint16_t)s) << 16;
  return x.f;
}

DEV void llds16(const void* g, void* lds) {
  __builtin_amdgcn_global_load_lds(
      (const __attribute__((address_space(1))) uint32_t*)g,
      (__attribute__((address_space(3))) uint32_t*)lds, 16, 0, 0);
}

// ---------------- weight fp32->bf16 ----------------
__global__ __launch_bounds__(256)
void k_wconv(const float* __restrict__ qw, const float* __restrict__ pw,
             const float* __restrict__ f1, const float* __restrict__ f2,
             short* __restrict__ o) {
  const int i = blockIdx.x * 256 + threadIdx.x;
  float v;
  if (i < 196608) v = qw[i];
  else if (i < 262144) v = pw[i - 196608];
  else if (i < 524288) v = f1[i - 262144];
  else v = f2[i - 524288];
  o[i] = f2bf(v);
}

// ---------------- LN1 + window partition ----------------
__global__ __launch_bounds__(256)
void k_ln1(const float* __restrict__ x, const float* __restrict__ nw,
           const float* __restrict__ nb, short* __restrict__ T) {
  __shared__ float wS[256], bS[256];
  const int tid = threadIdx.x;
  const int wdw = blockIdx.x;
  const int bb = wdw >> 10, rem = wdw & 1023, wy = rem >> 5, wx = rem & 31;
  wS[tid] = nw[tid];
  bS[tid] = nb[tid];
  __syncthreads();
  const int g = tid >> 4, l16 = tid & 15;
  #pragma unroll
  for (int it = 0; it < 4; ++it) {
    const int t = it * 16 + g;
    const int gy = (wy << 3) + (t >> 3), gx = (wx << 3) + (t & 7);
    const size_t rrow = ((size_t)bb * 256 + gy) * 256 + gx;
    const float4* xv4 = (const float4*)(x + rrow * 256);
    float4 v[4];
    float s = 0.f, ss = 0.f;
    #pragma unroll
    for (int j = 0; j < 4; ++j) {
      v[j] = xv4[l16 * 4 + j];
      s  += v[j].x + v[j].y + v[j].z + v[j].w;
      ss += v[j].x * v[j].x + v[j].y * v[j].y + v[j].z * v[j].z + v[j].w * v[j].w;
    }
    #pragma unroll
    for (int m = 1; m < 16; m <<= 1) {
      s  += __shfl_xor(s, m);
      ss += __shfl_xor(ss, m);
    }
    const float mean = s * 0.00390625f;
    const float var  = ss * 0.00390625f - mean * mean;
    const float rs   = rsqrtf(var + 1e-5f);
    short tmp[16];
    #pragma unroll
    for (int j = 0; j < 4; ++j) {
      const float* vp = (const float*)&v[j];
      #pragma unroll
      for (int e = 0; e < 4; ++e) {
        const int c0 = l16 * 16 + j * 4 + e;
        tmp[j * 4 + e] = f2bf((vp[e] - mean) * rs * wS[c0] + bS[c0]);
      }
    }
    short8* dg = (short8*)(T + ((size_t)wdw * 64 + t) * 256 + l16 * 16);
    dg[0] = ((short8*)tmp)[0];
    dg[1] = ((short8*)tmp)[1];
  }
}

// ---------------- DFT of qkv rows via MFMA ----------------
__global__ __launch_bounds__(256)
void k_dft(short* __restrict__ QKV, const float* __restrict__ qkvb) {
  __shared__ short F[80 * 72];
  __shared__ short sbuf[10880];   // Xt[128][72] then yf[80][136]
  const int tid = threadIdx.x;
  const int w = tid >> 6, l = tid & 63;
  const int lr = l & 15, lg = l >> 4;
  const int wdw = blockIdx.y, ct = blockIdx.x;
  const size_t base = (size_t)wdw * 130;
  for (int i = tid; i < 80 * 64; i += 256) {
    const int row = i >> 6, n = i & 63;
    float v = 0.f;
    if (row < 33) v = 0.125f * cosf((float)((row * n) & 63) * TWO_PI_64);
    else if (row < 66) v = -0.125f * sinf((float)(((row - 33) * n) & 63) * TWO_PI_64);
    F[row * 72 + n] = f2bf(v);
  }
  short* Xt = sbuf;
  #pragma unroll
  for (int i = 0; i < 4; ++i) {
    const int cc = i * 256 + tid;
    const int tok = cc >> 4, c8 = cc & 15;
    const short8 v = *(const short8*)(QKV + (base + tok) * 768 + ct * 128 + c8 * 8);
    const int sw = (c8 & 3) << 3;
    #pragma unroll
    for (int j = 0; j < 8; ++j)
      Xt[(c8 * 8 + j) * 72 + (tok ^ sw)] = v[j];
  }
  __syncthreads();
  const int wcol = w << 5;
  f32x4 acc[5][2] = {};
  #pragma unroll
  for (int kk = 0; kk < 2; ++kk) {
    short8 af[5], bfr[2];
    #pragma unroll
    for (int mi = 0; mi < 5; ++mi)
      af[mi] = *(const short8*)(F + ((mi << 4) + lr) * 72 + (kk << 5) + (lg << 3));
    #pragma unroll
    for (int ni = 0; ni < 2; ++ni) {
      const int col = wcol + (ni << 4) + lr;
      const int sw = ((col >> 3) & 3) << 3;
      bfr[ni] = *(const short8*)(Xt + col * 72 + (((kk << 5) + (lg << 3)) ^ sw));
    }
    #pragma unroll
    for (int mi = 0; mi < 5; ++mi)
      #pragma unroll
      for (int ni = 0; ni < 2; ++ni)
        acc[mi][ni] = __builtin_amdgcn_mfma_f32_16x16x32_bf16(af[mi], bfr[ni], acc[mi][ni], 0, 0, 0);
  }
  __syncthreads();
  short* yf = sbuf;
  #pragma unroll
  for (int mi = 0; mi < 5; ++mi)
    #pragma unroll
    for (int ni = 0; ni < 2; ++ni)
      #pragma unroll
      for (int r = 0; r < 4; ++r)
        yf[((mi << 4) + (lg << 2) + r) * 136 + wcol + (ni << 4) + lr] = f2bf(acc[mi][ni][r]);
  __syncthreads();
  for (int cc = tid; cc < 66 * 16; cc += 256) {
    const int tok = cc >> 4, off = cc & 15;
    const short8 v = *(const short8*)(yf + tok * 136 + off * 8);
    const float bs = (tok == 0) ? -7.f : 1.f;
    short8 o;
    #pragma unroll
    for (int j = 0; j < 8; ++j)
      o[j] = f2bf(bf2f(v[j]) + bs * qkvb[ct * 128 + off * 8 + j]);
    *(short8*)(QKV + (base + 64 + tok) * 768 + ct * 128 + off * 8) = o;
  }
}

// ---------------- 128x128 MFMA GEMM (global_load_lds staging) ----------------
template<int EPI>
__global__ __launch_bounds__(256)
void gemm128(const short* __restrict__ A, const short* __restrict__ Bt,
             const float* __restrict__ bias, const float* __restrict__ addf,
             short* __restrict__ outb, float* __restrict__ outf,
             const int N, const int K, const int lda, const int ldb) {
  __shared__ short As[128 * 32];
  __shared__ short Bs[128 * 32];
  const int tid = threadIdx.x;
  const int w = tid >> 6, l = tid & 63;
  const int lr = l & 15, lg = l >> 4;
  const int bm = blockIdx.y << 7, bn = blockIdx.x << 7;
  const int wm = (w >> 1) << 6, wn = (w & 1) << 6;
  f32x4 acc[4][4] = {};
  const int rloc = l >> 2, kc = (l & 3) << 3;
  for (int kt = 0; kt < K; kt += 32) {
    #pragma unroll
    for (int i = 0; i < 2; ++i) {
      const int seg = i * 4 + w;
      const int row = (seg << 4) + rloc;
      llds16(A  + (size_t)(bm + row) * lda + kt + kc, As + seg * 512);
      llds16(Bt + (size_t)(bn + row) * ldb + kt + kc, Bs + seg * 512);
    }
    __syncthreads();
    short8 af[4], bfr[4];
    #pragma unroll
    for (int mi = 0; mi < 4; ++mi)
      af[mi] = *(const short8*)(As + ((wm + (mi << 4) + lr) << 5) + (lg << 3));
    #pragma unroll
    for (int ni = 0; ni < 4; ++ni)
      bfr[ni] = *(const short8*)(Bs + ((wn + (ni << 4) + lr) << 5) + (lg << 3));
    #pragma unroll
    for (int mi = 0; mi < 4; ++mi)
      #pragma unroll
      for (int ni = 0; ni < 4; ++ni)
        acc[mi][ni] = __builtin_amdgcn_mfma_f32_16x16x32_bf16(af[mi], bfr[ni], acc[mi][ni], 0, 0, 0);
    __syncthreads();
  }
  #pragma unroll
  for (int mi = 0; mi < 4; ++mi) {
    #pragma unroll
    for (int ni = 0; ni < 4; ++ni) {
      const f32x4 v = acc[mi][ni];
      const int col = bn + wn + (ni << 4) + lr;
      const int row0 = bm + wm + (mi << 4) + (lg << 2);
      const float bc = (EPI == 4) ? 0.f : bias[col];
      #pragma unroll
      for (int r = 0; r < 4; ++r) {
        const int row = row0 + r;
        float val = v[r] + bc;
        if (EPI == 0) {
          const size_t orow = (size_t)((row >> 6) * 130) + (row & 63);
          outb[orow * N + col] = f2bf(val);
        } else if (EPI == 2) {
          float gl = 0.5f * val * (1.0f + erff(val * 0.7071067811865475f));
          outb[(size_t)row * N + col] = f2bf(gl);
        } else if (EPI == 1) {
          const int ww = row >> 6, t = row & 63;
          const int b2 = ww >> 10, rem = ww & 1023;
          const int gy = ((rem >> 5) << 3) + (t >> 3);
          const int gx = ((rem & 31) << 3) + (t & 7);
          const size_t rr = ((size_t)b2 * 256 + gy) * 256 + gx;
          outf[rr * 256 + col] = val + addf[rr * 256 + col];
        } else if (EPI == 3) {
          outf[(size_t)row * N + col] = val + addf[(size_t)row * N + col];
        } else {
          outf[(size_t)row * N + col] += val;
        }
      }
    }
  }
}

// ---------------- spatial window attention (4 waves = 4 heads) ----------------
__global__ __launch_bounds__(256)
void attn_spatial(const short* __restrict__ QKV, const float* __restrict__ rpb,
                  short* __restrict__ Yw, const size_t yrow_base) {
  constexpr int LDP = 72;
  __shared__ short vt_s[4 * 32 * LDP];
  __shared__ short pl_s[4 * 64 * LDP];
  const int tid = threadIdx.x;
  const int w = tid >> 6, l = tid & 63;
  const int lr = l & 15, lg = l >> 4;
  const int w_l = blockIdx.x;
  const int h = blockIdx.y * 4 + w;
  const size_t rowbase = (size_t)w_l * 130;
  short* vt = vt_s + w * 32 * LDP;
  short* pl = pl_s + w * 64 * LDP;
  short* ostage = pl_s;

  #pragma unroll
  for (int i = 0; i < 4; ++i) {
    const int chunk = i * 64 + l;
    const int tok = chunk >> 2, d0 = (chunk & 3) << 3;
    const short8 vv = *(const short8*)(QKV + (rowbase + tok) * 768 + 512 + h * 32 + d0);
    #pragma unroll
    for (int j = 0; j < 8; ++j) vt[(d0 + j) * LDP + tok] = vv[j];
  }
  short8 bq[4], akf[4];
  #pragma unroll
  for (int ni = 0; ni < 4; ++ni)
    bq[ni] = *(const short8*)(QKV + (rowbase + (ni << 4) + lr) * 768 + h * 32 + (lg << 3));
  #pragma unroll
  for (int mi = 0; mi < 4; ++mi)
    akf[mi] = *(const short8*)(QKV + (rowbase + (mi << 4) + lr) * 768 + 256 + h * 32 + (lg << 3));

  #pragma unroll
  for (int ni = 0; ni < 4; ++ni) {
    f32x4 s[4];
    #pragma unroll
    for (int mi = 0; mi < 4; ++mi) {
      f32x4 z = {};
      s[mi] = __builtin_amdgcn_mfma_f32_16x16x32_bf16(akf[mi], bq[ni], z, 0, 0, 0);
    }
    const int q = (ni << 4) + lr;
    float lv[4][4];
    float mx = -3.0e30f;
    #pragma unroll
    for (int mi = 0; mi < 4; ++mi) {
      #pragma unroll
      for (int r = 0; r < 4; ++r) {
        const int mm = (mi << 4) + (lg << 2) + r;
        const int dy = (q >> 3) - (mm >> 3) + 7;
        const int dx = (q & 7) - (mm & 7) + 7;
        float tt = s[mi][r] * ATT_SCALE + rpb[(dy * 15 + dx) * 8 + h];
        lv[mi][r] = tt;
        mx = fmaxf(mx, tt);
      }
    }
    mx = fmaxf(mx, __shfl_xor(mx, 16));
    mx = fmaxf(mx, __shfl_xor(mx, 32));
    float sum = 0.f;
    #pragma unroll
    for (int mi = 0; mi < 4; ++mi)
      #pragma unroll
      for (int r = 0; r < 4; ++r) {
        const float p = __expf(lv[mi][r] - mx);
        lv[mi][r] = p;
        sum += p;
      }
    sum += __shfl_xor(sum, 16);
    sum += __shfl_xor(sum, 32);
    const float inv = 1.0f / sum;
    #pragma unroll
    for (int mi = 0; mi < 4; ++mi) {
      short4v pk;
      #pragma unroll
      for (int r = 0; r < 4; ++r) pk[r] = f2bf(lv[mi][r] * inv);
      *(short4v*)(pl + q * LDP + (mi << 4) + (lg << 2)) = pk;
    }
  }
  __syncthreads();

  f32x4 o[2][4] = {};
  #pragma unroll
  for (int ks = 0; ks < 2; ++ks) {
    short8 av[2], pb[4];
    #pragma unroll
    for (int di = 0; di < 2; ++di)
      av[di] = *(const short8*)(vt + ((di << 4) + lr) * LDP + (ks << 5) + (lg << 3));
    #pragma unroll
    for (int ni = 0; ni < 4; ++ni)
      pb[ni] = *(const short8*)(pl + ((ni << 4) + lr) * LDP + (ks << 5) + (lg << 3));
    #pragma unroll
    for (int di = 0; di < 2; ++di)
      #pragma unroll
      for (int ni = 0; ni < 4; ++ni)
        o[di][ni] = __builtin_amdgcn_mfma_f32_16x16x32_bf16(av[di], pb[ni], o[di][ni], 0, 0, 0);
  }
  __syncthreads();
  #pragma unroll
  for (int di = 0; di < 2; ++di)
    #pragma unroll
    for (int ni = 0; ni < 4; ++ni) {
      const int q = (ni << 4) + lr;
      short4v ov;
      #pragma unroll
      for (int r = 0; r < 4; ++r) ov[r] = f2bf(o[di][ni][r]);
      *(short4v*)(ostage + q * 128 + w * 32 + (di << 4) + (lg << 2)) = ov;
    }
  __syncthreads();
  const size_t obase = (yrow_base + (size_t)w_l * 64) * 256 + (size_t)blockIdx.y * 128;
  for (int cc = tid; cc < 64 * 16; cc += 256) {
    const int tok = cc >> 4, off = cc & 15;
    const short8 vv = *(const short8*)(ostage + tok * 128 + off * 8);
    *(short8*)(Yw + obase + (size_t)tok * 256 + off * 8) = vv;
  }
}

// ---------------- spectral attention + MFMA irfft ----------------
// Per window: 2 passes x 4 waves (heads). Y_spec^T[d][n] = (PV)^T[d][q] @ G[n][q],
// G (irfft matrix incl. 0.125 scale + Hermitian weights) held in registers.
__global__ __launch_bounds__(256)
void attn_spec(const short* __restrict__ QKV, short* __restrict__ Yw,
               const size_t yrow_base) {
  constexpr int NTOK = 66, LDP = 104;
  constexpr int FQ = 5, FK = 6, KS = 3;
  __shared__ short vt_s[4 * 32 * LDP];   // 26,624 B (also PVt per wave)
  __shared__ short pl_s[4 * 80 * LDP];   // 66,560 B (also ystage 64x136)
  const int tid = threadIdx.x;
  const int w = tid >> 6, l = tid & 63;
  const int lr = l & 15, lg = l >> 4;
  const int w_l = blockIdx.x;
  const size_t rowbase = (size_t)w_l * 130 + 64;
  short* vt = vt_s + w * 32 * LDP;
  short* pl = pl_s + w * 80 * LDP;

  // G fragments (B-operand): rows n=(ni2<<4)+lr, k-dim q=(ks2<<5)+(lg<<3)+j
  short8 gfr[4][3];
  #pragma unroll
  for (int ni2 = 0; ni2 < 4; ++ni2) {
    const int n = (ni2 << 4) + lr;
    #pragma unroll
    for (int ks2 = 0; ks2 < 3; ++ks2) {
      short8 gg;
      #pragma unroll
      for (int j = 0; j < 8; ++j) {
        const int q = (ks2 << 5) + (lg << 3) + j;
        float g = 0.f;
        if (q == 0) g = 0.125f;
        else if (q < 32) g = 0.25f * __cosf((float)((n * q) & 63) * TWO_PI_64);
        else if (q == 32) g = (n & 1) ? -0.125f : 0.125f;
        else if (q >= 34 && q <= 64) g = -0.25f * __sinf((float)((n * (q - 33)) & 63) * TWO_PI_64);
        gg[j] = f2bf(g);
      }
      gfr[ni2][ks2] = gg;
    }
  }

  for (int pass = 0; pass < 2; ++pass) {
    const int h = pass * 4 + w;
    // stage V^T (zero k-padding)
    #pragma unroll
    for (int i = 0; i < 6; ++i) {
      const int chunk = i * 64 + l;
      const int tok = chunk >> 2, d0 = (chunk & 3) << 3;
      short8 vv = {};
      if (tok < NTOK)
        vv = *(const short8*)(QKV + (rowbase + tok) * 768 + 512 + h * 32 + d0);
      #pragma unroll
      for (int j = 0; j < 8; ++j) vt[(d0 + j) * LDP + tok] = vv[j];
    }
    short8 bq[FQ], akf[FK];
    #pragma unroll
    for (int ni = 0; ni < FQ; ++ni) {
      const int q = (ni << 4) + lr;
      short8 z = {};
      bq[ni] = (q < NTOK)
        ? *(const short8*)(QKV + (rowbase + q) * 768 + h * 32 + (lg << 3)) : z;
    }
    #pragma unroll
    for (int mi = 0; mi < FK; ++mi) {
      const int mm = (mi << 4) + lr;
      short8 z = {};
      akf[mi] = (mm < NTOK)
        ? *(const short8*)(QKV + (rowbase + mm) * 768 + 256 + h * 32 + (lg << 3)) : z;
    }
    // S^T + softmax -> P in pl (wave-local)
    #pragma unroll
    for (int ni = 0; ni < FQ; ++ni) {
      f32x4 s[FK];
      #pragma unroll
      for (int mi = 0; mi < FK; ++mi) {
        f32x4 z = {};
        s[mi] = __builtin_amdgcn_mfma_f32_16x16x32_bf16(akf[mi], bq[ni], z, 0, 0, 0);
      }
      const int q = (ni << 4) + lr;
      float lv[FK][4];
      float mx = -3.0e30f;
      #pragma unroll
      for (int mi = 0; mi < FK; ++mi)
        #pragma unroll
        for (int r = 0; r < 4; ++r) {
          const int mm = (mi << 4) + (lg << 2) + r;
          float tt = s[mi][r] * ATT_SCALE;
          if (mm >= NTOK) tt = -3.0e30f;
          lv[mi][r] = tt;
          mx = fmaxf(mx, tt);
        }
      mx = fmaxf(mx, __shfl_xor(mx, 16));
      mx = fmaxf(mx, __shfl_xor(mx, 32));
      float sum = 0.f;
      #pragma unroll
      for (int mi = 0; mi < FK; ++mi)
        #pragma unroll
        for (int r = 0; r < 4; ++r) {
          const float p = __expf(lv[mi][r] - mx);
          lv[mi][r] = p;
          sum += p;
        }
      sum += __shfl_xor(sum, 16);
      sum += __shfl_xor(sum, 32);
      const float inv = 1.0f / sum;
      #pragma unroll
      for (int mi = 0; mi < FK; ++mi) {
        short4v pk;
        #pragma unroll
        for (int r = 0; r < 4; ++r) pk[r] = f2bf(lv[mi][r] * inv);
        *(short4v*)(pl + q * LDP + (mi << 4) + (lg << 2)) = pk;
      }
    }
    // PV: o[d][q] = V^T @ P^T (wave-local LDS, no barrier needed)
    f32x4 o[2][FQ] = {};
    #pragma unroll
    for (int ks = 0; ks < KS; ++ks) {
      short8 av[2], pb[FQ];
      #pragma unroll
      for (int di = 0; di < 2; ++di)
        av[di] = *(const short8*)(vt + ((di << 4) + lr) * LDP + (ks << 5) + (lg << 3));
      #pragma unroll
      for (int ni = 0; ni < FQ; ++ni)
        pb[ni] = *(const short8*)(pl + ((ni << 4) + lr) * LDP + (ks << 5) + (lg << 3));
      #pragma unroll
      for (int di = 0; di < 2; ++di)
        #pragma unroll
        for (int ni = 0; ni < FQ; ++ni)
          o[di][ni] = __builtin_amdgcn_mfma_f32_16x16x32_bf16(av[di], pb[ni], o[di][ni], 0, 0, 0);
    }
    // PVt (bf16) over vt region (wave-local). q-cols 80..95 remain zero (V pad).
    #pragma unroll
    for (int di = 0; di < 2; ++di)
      #pragma unroll
      for (int ni = 0; ni < FQ; ++ni)
        #pragma unroll
        for (int r = 0; r < 4; ++r)
          vt[((di << 4) + (lg << 2) + r) * LDP + (ni << 4) + lr] = f2bf(o[di][ni][r]);
    // irfft via MFMA: Yspec^T[d][n] = PVt[d][q] . G[n][q]
    f32x4 o2[2][4] = {};
    #pragma unroll
    for (int ks2 = 0; ks2 < 3; ++ks2) {
      short8 av2[2];
      #pragma unroll
      for (int mi2 = 0; mi2 < 2; ++mi2)
        av2[mi2] = *(const short8*)(vt + ((mi2 << 4) + lr) * LDP + (ks2 << 5) + (lg << 3));
      #pragma unroll
      for (int mi2 = 0; mi2 < 2; ++mi2)
        #pragma unroll
        for (int ni2 = 0; ni2 < 4; ++ni2)
          o2[mi2][ni2] = __builtin_amdgcn_mfma_f32_16x16x32_bf16(av2[mi2], gfr[ni2][ks2], o2[mi2][ni2], 0, 0, 0);
    }
    __syncthreads();                 // all waves done with pl before ystage aliases it
    // stage Yspec (n rows, 128 head-cols of this pass) into pl_s
    short* yst = pl_s;
    #pragma unroll
    for (int mi2 = 0; mi2 < 2; ++mi2)
      #pragma unroll
      for (int ni2 = 0; ni2 < 4; ++ni2)
        #pragma unroll
        for (int r = 0; r < 4; ++r)
          yst[((ni2 << 4) + lr) * 136 + (w << 5) + (mi2 << 4) + (lg << 2) + r] =
              f2bf(o2[mi2][ni2][r]);
    __syncthreads();
    // coalesced RMW of Yw
    const size_t ybase = (yrow_base + (size_t)w_l * 64) * 256 + (size_t)pass * 128;
    for (int cc = tid; cc < 64 * 16; cc += 256) {
      const int n = cc >> 4, off = (cc & 15) << 3;
      short8 yv = *(short8*)(Yw + ybase + (size_t)n * 256 + off);
      const short8 av = *(const short8*)(yst + n * 136 + off);
      short8 ov;
      #pragma unroll
      for (int j = 0; j < 8; ++j) ov[j] = f2bf(bf2f(yv[j]) + bf2f(av[j]));
      *(short8*)(Yw + ybase + (size_t)n * 256 + off) = ov;
    }
    __syncthreads();                 // before next pass overwrites pl/vt
  }
}

// ---------------- LN2 ----------------
__global__ __launch_bounds__(256)
void k_ln2(const float* __restrict__ xin, const float* __restrict__ nw,
           const float* __restrict__ nb, short* __restrict__ t2) {
  __shared__ float wS[256], bS[256];
  const int tid = threadIdx.x;
  wS[tid] = nw[tid];
  bS[tid] = nb[tid];
  __syncthreads();
  const int g = tid >> 4, l16 = tid & 15;
  const size_t row = (size_t)blockIdx.x * 16 + g;
  const float4* xv4 = (const float4*)(xin + row * 256);
  float4 v[4];
  float s = 0.f, ss = 0.f;
  #pragma unroll
  for (int j = 0; j < 4; ++j) {
    v[j] = xv4[l16 * 4 + j];
    s  += v[j].x + v[j].y + v[j].z + v[j].w;
    ss += v[j].x * v[j].x + v[j].y * v[j].y + v[j].z * v[j].z + v[j].w * v[j].w;
  }
  #pragma unroll
  for (int m = 1; m < 16; m <<= 1) {
    s  += __shfl_xor(s, m);
    ss += __shfl_xor(ss, m);
  }
  const float mean = s * 0.00390625f;
  const float var  = ss * 0.00390625f - mean * mean;
  const float rs   = rsqrtf(var + 1e-5f);
  short tmp[16];
  #pragma unroll
  for (int j = 0; j < 4; ++j) {
    const float* vp = (const float*)&v[j];
    #pragma unroll
    for (int e = 0; e < 4; ++e) {
      const int c0 = l16 * 16 + j * 4 + e;
      tmp[j * 4 + e] = f2bf((vp[e] - mean) * rs * wS[c0] + bS[c0]);
    }
  }
  short8* dg = (short8*)(t2 + row * 256 + l16 * 16);
  dg[0] = ((short8*)tmp)[0];
  dg[1] = ((short8*)tmp)[1];
}

extern "C" void kernel_launch(void* const* d_in, const int* in_sizes, int n_in,
                              void* d_out, int out_size, void* d_ws, size_t ws_size,
                              hipStream_t stream) {
  const float* x    = (const float*)d_in[0];
  const float* n1w  = (const float*)d_in[2];
  const float* n1b  = (const float*)d_in[3];
  const float* qkvw = (const float*)d_in[4];
  const float* qkvb = (const float*)d_in[5];
  const float* rpb  = (const float*)d_in[6];
  const float* prw  = (const float*)d_in[7];
  const float* prb  = (const float*)d_in[8];
  const float* n2w  = (const float*)d_in[9];
  const float* n2b  = (const float*)d_in[10];
  const float* f1w  = (const float*)d_in[11];
  const float* f1b  = (const float*)d_in[12];
  const float* f2w  = (const float*)d_in[13];
  const float* f2b  = (const float*)d_in[14];
  float* out = (float*)d_out;
  char* ws = (char*)d_ws;

  short* T    = (short*)(ws);                       // 67,108,864
  short* QKVc = (short*)(ws + 67108864ULL);         // 102,236,160 (512-window chunk)
  short* Yw   = (short*)(ws + 169345024ULL);        // 67,108,864
  float* X2   = (float*)(ws);                       // 134,217,728 (over dead T+QKVc head)
  short* T2   = (short*)(ws + 134217728ULL);        // 67,108,864
  short* HIDq = (short*)(ws + 201326592ULL);        // 67,108,864
  short* WB   = (short*)(ws + 268435456ULL);        // 1,572,864

  const short* QKV_WB = WB;
  const short* PR_WB  = WB + 196608;
  const short* F1_WB  = WB + 262144;
  const short* F2_WB  = WB + 524288;

  k_wconv<<<dim3(3072), dim3(256), 0, stream>>>(qkvw, prw, f1w, f2w, WB);
  k_ln1<<<dim3(2048), dim3(256), 0, stream>>>(x, n1w, n1b, T);

  for (int c = 0; c < 4; ++c) {
    const short* Tc = T + (size_t)c * 32768 * 256;
    gemm128<0><<<dim3(6, 256), dim3(256), 0, stream>>>(
        Tc, QKV_WB, qkvb, nullptr, QKVc, nullptr, 768, 256, 256, 256);
    k_dft<<<dim3(6, 512), dim3(256), 0, stream>>>(QKVc, qkvb);
    attn_spatial<<<dim3(512, 2), dim3(256), 0, stream>>>(
        QKVc, rpb, Yw, (size_t)c * 32768);
    attn_spec<<<dim3(512), dim3(256), 0, stream>>>(
        QKVc, Yw, (size_t)c * 32768);
  }

  gemm128<1><<<dim3(2, 1024), dim3(256), 0, stream>>>(
      Yw, PR_WB, prb, x, nullptr, X2, 256, 256, 256, 256);
  k_ln2<<<dim3(8192), dim3(256), 0, stream>>>(X2, n2w, n2b, T2);

  for (int p = 0; p < 4; ++p) {
    gemm128<2><<<dim3(2, 1024), dim3(256), 0, stream>>>(
        T2, F1_WB + p * 65536, f1b + p * 256, nullptr, HIDq, nullptr, 256, 256, 256, 256);
    if (p == 0) {
      gemm128<3><<<dim3(2, 1024), dim3(256), 0, stream>>>(
          HIDq, F2_WB + p * 256, f2b, X2, nullptr, out, 256, 256, 256, 1024);
    } else {
      gemm128<4><<<dim3(2, 1024), dim3(256), 0, stream>>>(
          HIDq, F2_WB + p * 256, f2b, X2, nullptr, out, 256, 256, 256, 1024);
    }
  }

  (void)in_sizes; (void)n_in; (void)out_size; (void)ws_size;
}